// Round 2
// baseline (541.869 us; speedup 1.0000x reference)
//
#include <hip/hip_runtime.h>
#include <math.h>

#define NB 32
#define NN 262144
#define NG 256
#define NC 128            // chunks per batch (sort passes)
#define CH (NN/NC)        // 2048 elements per chunk
#define CD 64             // chunks per batch, apply pass
#define ELD (NN/CD)       // 4096 elements per apply block

// Order-preserving float<->uint mapping for integer atomic min/max (exact)
static __device__ __forceinline__ unsigned encf(float x){
  unsigned b = __float_as_uint(x);
  return (b & 0x80000000u) ? ~b : (b | 0x80000000u);
}
static __device__ __forceinline__ float decf(unsigned u){
  unsigned b = (u & 0x80000000u) ? (u ^ 0x80000000u) : ~u;
  return __uint_as_float(b);
}

__global__ __launch_bounds__(256) void k_init(unsigned* __restrict__ gmin,
                                              unsigned* __restrict__ gmax){
  int i = blockIdx.x * 256 + threadIdx.x;
  if (i < NB*NG){
    gmin[i] = 0xFF800000u;  // encf(+inf)
    gmax[i] = 0x007FFFFFu;  // encf(-inf)
  }
}

// Pass 1: per-(batch,chunk,group) counts + per-(batch,group) exact min/max
__global__ __launch_bounds__(256) void k_count(const float* __restrict__ pr,
                                               const int* __restrict__ vr,
                                               unsigned* __restrict__ cnt,
                                               unsigned* __restrict__ gmin,
                                               unsigned* __restrict__ gmax){
  __shared__ unsigned scnt[NG];
  __shared__ unsigned smin[NG];
  __shared__ unsigned smax[NG];
  const int t = threadIdx.x;
  scnt[t] = 0u; smin[t] = 0xFF800000u; smax[t] = 0x007FFFFFu;
  __syncthreads();

  const int b = blockIdx.x / NC;
  const int c = blockIdx.x % NC;
  const size_t base = (size_t)b*NN + (size_t)c*CH;
  const float4* p4 = (const float4*)(pr + base);
  const int4*  v4 = (const int4*)(vr + base);

#pragma unroll
  for (int i = 0; i < CH/1024; i++){
    float4 p = p4[i*256 + t];
    int4   v = v4[i*256 + t];
#define ACC1(pp, gg) do{ \
      unsigned e = encf(pp); \
      atomicMin(&smin[gg], e); \
      atomicMax(&smax[gg], e); \
      atomicAdd(&scnt[gg], 1u); \
    }while(0)
    ACC1(p.x, v.x); ACC1(p.y, v.y); ACC1(p.z, v.z); ACC1(p.w, v.w);
#undef ACC1
  }
  __syncthreads();
  cnt[(size_t)(b*NC + c)*NG + t] = scnt[t];
  atomicMin(&gmin[b*NG + t], smin[t]);
  atomicMax(&gmax[b*NG + t], smax[t]);
}

// Pass 2: rewrite cnt in-place into absolute scatter offsets; emit group base/len
__global__ __launch_bounds__(256) void k_offsets(unsigned* __restrict__ cnt,
                                                 unsigned* __restrict__ grpbase,
                                                 unsigned* __restrict__ grplen){
  const int b = blockIdx.x;
  const int g = threadIdx.x;
  unsigned tot = 0;
  for (int c = 0; c < NC; c++) tot += cnt[(size_t)(b*NC + c)*NG + g];

  __shared__ unsigned ss[NG];
  ss[g] = tot; __syncthreads();
  for (int d = 1; d < NG; d <<= 1){
    unsigned v = (g >= d) ? ss[g - d] : 0u;
    __syncthreads();
    ss[g] += v;
    __syncthreads();
  }
  unsigned base = ss[g] - tot;   // exclusive prefix over groups

  unsigned run = base;
  for (int c = 0; c < NC; c++){
    size_t idx = (size_t)(b*NC + c)*NG + g;
    unsigned x = cnt[idx];
    cnt[idx] = run;
    run += x;
  }
  grpbase[b*NG + g] = base;
  grplen [b*NG + g] = tot;
}

// Pass 3: stable scatter of pr by group id (one wave per chunk, element order preserved)
__global__ __launch_bounds__(64) void k_scatter(const float* __restrict__ pr,
                                                const int* __restrict__ vr,
                                                const unsigned* __restrict__ off,
                                                float* __restrict__ sorted){
  __shared__ unsigned scnt[NG];
  const int lane = threadIdx.x;
  const int b = blockIdx.x / NC;
  const int c = blockIdx.x % NC;

#pragma unroll
  for (int k = 0; k < NG/64; k++)
    scnt[k*64 + lane] = off[(size_t)(b*NC + c)*NG + k*64 + lane];
  __syncthreads();

  const size_t base = (size_t)b*NN + (size_t)c*CH;
  float* dst = sorted + (size_t)b*NN;
  const unsigned long long below = (lane == 0) ? 0ull : ((1ull << lane) - 1ull);

  for (int s = 0; s < CH/64; s++){
    float p = pr[base + s*64 + lane];
    int   g = vr[base + s*64 + lane];
    // match-any emulation: mask of lanes with the same 8-bit key
    unsigned long long mask = ~0ull;
#pragma unroll
    for (int bit = 0; bit < 8; bit++){
      int bv = (g >> bit) & 1;
      unsigned long long bal = __ballot(bv);
      mask &= bv ? bal : ~bal;
    }
    int rank = __popcll(mask & below);
    unsigned old = scnt[g];                   // all lanes read pre-update value
    if (rank == 0) scnt[g] = old + (unsigned)__popcll(mask);  // one leader per key
    dst[old + (unsigned)rank] = p;
  }
}

// Pass 4: sequential fp32 per-group sums (bit-exact element-order chain) + group pipeline
__global__ __launch_bounds__(256) void k_groups(const float* __restrict__ sorted,
                                                const unsigned* __restrict__ grpbase,
                                                const unsigned* __restrict__ grplen,
                                                const unsigned* __restrict__ gmin,
                                                const unsigned* __restrict__ gmax,
                                                const float* __restrict__ inp_means,
                                                const float* __restrict__ Wv,
                                                float4* __restrict__ params){
  const int b = blockIdx.x;
  const int g = threadIdx.x;
  __shared__ float vm[NG];
  __shared__ float vs[NG];

  const unsigned base = grpbase[b*NG + g];
  const unsigned len  = grplen [b*NG + g];
  const float* src = sorted + (size_t)b*NN + base;
  float s = 0.0f;
  for (unsigned i = 0; i < len; i++) s = __fadd_rn(s, src[i]);

  const float mnf = decf(gmin[b*NG + g]);
  const float mxf = decf(gmax[b*NG + g]);
  const float W0 = Wv[0], W1 = Wv[1];
  // empty group: len==0 -> s==0, matching where(vany, vsum, 0)
  float mean = __fdiv_rn(__fadd_rn(__fmul_rn(inp_means[b*NG + g], W0),
                                   __fmul_rn(s, W1)),
                         __fadd_rn(W0, W1));
  vm[g] = mean;
  __syncthreads();

  // stable rank == position after stable argsort
  int r = 0;
  for (int j = 0; j < NG; j++){
    float x = vm[j];
    r += (x < mean) || (x == mean && j < g);
  }
  vs[r] = mean;
  __syncthreads();

  float c0 = (r == 0)    ? vs[0]                     : vs[r-1];
  float c1 = vs[r];
  float c2 = (r == NG-1) ? __fmul_rn(vs[NG-1], 2.0f) : vs[r+1];
  float f0 = __fdiv_rn(__fadd_rn(c0, c1), 1.999f);
  float f1 = __fdiv_rn(__fadd_rn(c1, c2), 2.001f);

  bool ns = (mnf == mxf);
  float4 q;
  q.x = ns ? 0.0f : mnf;                       // vmin_use
  q.y = ns ? 1.0f : __fsub_rn(mxf, mnf);       // range_use
  q.z = ns ? 1.0f : __fsub_rn(f1, f0);         // (f1-f0)_use
  q.w = ns ? 0.0f : f0;                        // f0_use
  params[b*NG + g] = q;
}

// Pass 5: per-element apply, fp32 replicating reference op order (no contraction)
static __device__ __forceinline__ float apply_one(float p, int g, const float4* __restrict__ sp){
  float4 q = sp[g];
  float t1  = __fsub_rn(p, q.x);
  float t3  = __fdiv_rn(t1, q.y);
  float t5  = __fmul_rn(t3, q.z);
  float tmp = __fadd_rn(t5, q.w);
  bool bad = __builtin_isnan(tmp) || (tmp == 0.0f);
  float s = __fdiv_rn(p, bad ? 1.0f : tmp);
  bool bad2 = bad || __builtin_isnan(s) || __builtin_isinf(s);
  float sc = bad2 ? 0.0f : s;
  return __fmul_rn(p, sc);
}

__global__ __launch_bounds__(256) void k_apply(const float* __restrict__ pr,
                                               const int* __restrict__ vr,
                                               const float4* __restrict__ params,
                                               float* __restrict__ out){
  __shared__ float4 sp[NG];
  const int t = threadIdx.x;
  const int b = blockIdx.x / CD;
  const int c = blockIdx.x % CD;

  sp[t] = params[b*NG + t];
  __syncthreads();

  const size_t base = (size_t)b*NN + (size_t)c*ELD;
  const float4* p4 = (const float4*)(pr + base);
  const int4*  v4 = (const int4*)(vr + base);
  float4* o4 = (float4*)(out + base);

#pragma unroll
  for (int i = 0; i < ELD/1024; i++){
    float4 p = p4[i*256 + t];
    int4   v = v4[i*256 + t];
    float4 r;
    r.x = apply_one(p.x, v.x, sp);
    r.y = apply_one(p.y, v.y, sp);
    r.z = apply_one(p.z, v.z, sp);
    r.w = apply_one(p.w, v.w, sp);
    o4[i*256 + t] = r;
  }
}

extern "C" void kernel_launch(void* const* d_in, const int* in_sizes, int n_in,
                              void* d_out, int out_size, void* d_ws, size_t ws_size,
                              hipStream_t stream){
  const float* pr        = (const float*)d_in[0];
  const float* inp_means = (const float*)d_in[1];
  const int*   vr        = (const int*)d_in[2];
  const float* W         = (const float*)d_in[3];
  float* out = (float*)d_out;

  char* ws = (char*)d_ws;
  unsigned* cnt     = (unsigned*)(ws);                              // 4 MB
  unsigned* gmin    = (unsigned*)(ws + (size_t)NB*NC*NG*4);         // 32 KB
  unsigned* gmax    = (unsigned*)(ws + (size_t)NB*NC*NG*4 + 32768); // 32 KB
  unsigned* grpbase = (unsigned*)(ws + (size_t)NB*NC*NG*4 + 65536);
  unsigned* grplen  = (unsigned*)(ws + (size_t)NB*NC*NG*4 + 98304);
  float4*   params  = (float4*)  (ws + (size_t)NB*NC*NG*4 + 131072);// 128 KB
  // sorted values live in d_out (fully overwritten by k_apply afterwards)
  float* sorted = out;

  k_init   <<<(NB*NG + 255)/256, 256, 0, stream>>>(gmin, gmax);
  k_count  <<<NB*NC,             256, 0, stream>>>(pr, vr, cnt, gmin, gmax);
  k_offsets<<<NB,                 NG, 0, stream>>>(cnt, grpbase, grplen);
  k_scatter<<<NB*NC,              64, 0, stream>>>(pr, vr, cnt, sorted);
  k_groups <<<NB,                 NG, 0, stream>>>(sorted, grpbase, grplen, gmin, gmax,
                                                  inp_means, W, params);
  k_apply  <<<NB*CD,             256, 0, stream>>>(pr, vr, params, out);
}

// Round 3
// 333.778 us; speedup vs baseline: 1.6234x; 1.6234x over previous
//
#include <hip/hip_runtime.h>
#include <math.h>

#define NB 32
#define NN 262144
#define NG 256
#define NC 128            // chunks per batch (sort passes)
#define CH (NN/NC)        // 2048 elements per chunk
#define CD 64             // chunks per batch, apply pass
#define ELD (NN/CD)       // 4096 elements per apply block
#define LCAP 2048         // LDS floats per group in k_sum (mean len 1024, sigma~32)

// ---------------- Pass 1: per-(batch,chunk,group) counts ----------------
__global__ __launch_bounds__(256) void k_count(const int* __restrict__ vr,
                                               unsigned* __restrict__ cnt){
  __shared__ unsigned scnt[NG];
  const int t = threadIdx.x;
  scnt[t] = 0u;
  __syncthreads();

  const int b = blockIdx.x / NC;
  const int c = blockIdx.x % NC;
  const size_t base = (size_t)b*NN + (size_t)c*CH;
  const int4* v4 = (const int4*)(vr + base);

#pragma unroll
  for (int i = 0; i < CH/1024; i++){
    int4 v = v4[i*256 + t];
    atomicAdd(&scnt[v.x], 1u);
    atomicAdd(&scnt[v.y], 1u);
    atomicAdd(&scnt[v.z], 1u);
    atomicAdd(&scnt[v.w], 1u);
  }
  __syncthreads();
  cnt[(size_t)(b*NC + c)*NG + t] = scnt[t];
}

// ---- Pass 2: rewrite cnt into absolute scatter offsets; emit group base/len ----
__global__ __launch_bounds__(256) void k_offsets(unsigned* __restrict__ cnt,
                                                 unsigned* __restrict__ grpbase,
                                                 unsigned* __restrict__ grplen){
  const int b = blockIdx.x;
  const int g = threadIdx.x;
  unsigned tot = 0;
  for (int c = 0; c < NC; c++) tot += cnt[(size_t)(b*NC + c)*NG + g];

  __shared__ unsigned ss[NG];
  ss[g] = tot; __syncthreads();
  for (int d = 1; d < NG; d <<= 1){
    unsigned v = (g >= d) ? ss[g - d] : 0u;
    __syncthreads();
    ss[g] += v;
    __syncthreads();
  }
  unsigned base = ss[g] - tot;   // exclusive prefix over groups

  unsigned run = base;
  for (int c = 0; c < NC; c++){
    size_t idx = (size_t)(b*NC + c)*NG + g;
    unsigned x = cnt[idx];
    cnt[idx] = run;
    run += x;
  }
  grpbase[b*NG + g] = base;
  grplen [b*NG + g] = tot;
}

// ---- Pass 3: stable scatter of pr by group id (one wave per chunk, order kept) ----
__global__ __launch_bounds__(64) void k_scatter(const float* __restrict__ pr,
                                                const int* __restrict__ vr,
                                                const unsigned* __restrict__ off,
                                                float* __restrict__ sorted){
  __shared__ unsigned scnt[NG];
  const int lane = threadIdx.x;
  const int b = blockIdx.x / NC;
  const int c = blockIdx.x % NC;

#pragma unroll
  for (int k = 0; k < NG/64; k++)
    scnt[k*64 + lane] = off[(size_t)(b*NC + c)*NG + k*64 + lane];
  __syncthreads();

  const size_t base = (size_t)b*NN + (size_t)c*CH;
  float* dst = sorted + (size_t)b*NN;
  const unsigned long long below = (lane == 0) ? 0ull : ((1ull << lane) - 1ull);

  for (int s = 0; s < CH/64; s++){
    float p = pr[base + s*64 + lane];
    int   g = vr[base + s*64 + lane];
    // match-any emulation: mask of lanes with the same 8-bit key
    unsigned long long mask = ~0ull;
#pragma unroll
    for (int bit = 0; bit < 8; bit++){
      int bv = (g >> bit) & 1;
      unsigned long long bal = __ballot(bv);
      mask &= bv ? bal : ~bal;
    }
    int rank = __popcll(mask & below);
    unsigned old = scnt[g];                   // all lanes read pre-update value
    if (rank == 0) scnt[g] = old + (unsigned)__popcll(mask);  // one leader per key
    dst[old + (unsigned)rank] = p;
  }
}

// ---- Pass 4: one wave per (batch,group): stage group in LDS, lane0 runs the
//      bit-exact element-order fp32 chain; wave-reduce exact min/max ----
__global__ __launch_bounds__(64) void k_sum(const float* __restrict__ sorted,
                                            const unsigned* __restrict__ grpbase,
                                            const unsigned* __restrict__ grplen,
                                            float* __restrict__ gsum,
                                            float* __restrict__ gmn,
                                            float* __restrict__ gmx){
  __shared__ float sm[LCAP];
  const int lane = threadIdx.x;
  const int b = blockIdx.x / NG;
  const int g = blockIdx.x % NG;

  const unsigned base = grpbase[b*NG + g];
  const unsigned len  = grplen [b*NG + g];
  const float* src = sorted + (size_t)b*NN + base;

  float mn = INFINITY, mx = -INFINITY;
  for (unsigned i = lane; i < len; i += 64){
    float v = src[i];
    mn = fminf(mn, v);
    mx = fmaxf(mx, v);
    if (i < LCAP) sm[i] = v;
  }
#pragma unroll
  for (int d = 32; d > 0; d >>= 1){
    mn = fminf(mn, __shfl_down(mn, d));
    mx = fmaxf(mx, __shfl_down(mx, d));
  }
  __syncthreads();

  if (lane == 0){
    const unsigned lim = (len < LCAP) ? len : LCAP;
    float s = 0.0f;
    unsigned i = 0;
    for (; i + 8 <= lim; i += 8){
      // 8 LDS reads batched ahead of the dependent add chain
      float v0 = sm[i+0], v1 = sm[i+1], v2 = sm[i+2], v3 = sm[i+3];
      float v4 = sm[i+4], v5 = sm[i+5], v6 = sm[i+6], v7 = sm[i+7];
      s = __fadd_rn(s, v0); s = __fadd_rn(s, v1);
      s = __fadd_rn(s, v2); s = __fadd_rn(s, v3);
      s = __fadd_rn(s, v4); s = __fadd_rn(s, v5);
      s = __fadd_rn(s, v6); s = __fadd_rn(s, v7);
    }
    for (; i < lim; i++) s = __fadd_rn(s, sm[i]);
    for (unsigned j = lim; j < len; j++) s = __fadd_rn(s, src[j]); // safety tail
    gsum[b*NG + g] = s;
    gmn [b*NG + g] = mn;
    gmx [b*NG + g] = mx;
  }
}

// ---- Pass 5: per-batch group pipeline (blend, stable rank, f0/f1, no_scale) ----
__global__ __launch_bounds__(256) void k_pipeline(const float* __restrict__ gsum,
                                                  const float* __restrict__ gmn,
                                                  const float* __restrict__ gmx,
                                                  const float* __restrict__ inp_means,
                                                  const float* __restrict__ Wv,
                                                  float4* __restrict__ params){
  const int b = blockIdx.x;
  const int g = threadIdx.x;
  __shared__ float vm[NG];
  __shared__ float vs[NG];

  const float s   = gsum[b*NG + g];   // empty group: len==0 -> s==0 (matches where(vany,...))
  const float mnf = gmn [b*NG + g];
  const float mxf = gmx [b*NG + g];
  const float W0 = Wv[0], W1 = Wv[1];
  float mean = __fdiv_rn(__fadd_rn(__fmul_rn(inp_means[b*NG + g], W0),
                                   __fmul_rn(s, W1)),
                         __fadd_rn(W0, W1));
  vm[g] = mean;
  __syncthreads();

  // stable rank == position after stable argsort
  int r = 0;
  for (int j = 0; j < NG; j++){
    float x = vm[j];
    r += (x < mean) || (x == mean && j < g);
  }
  vs[r] = mean;
  __syncthreads();

  float c0 = (r == 0)    ? vs[0]                     : vs[r-1];
  float c1 = vs[r];
  float c2 = (r == NG-1) ? __fmul_rn(vs[NG-1], 2.0f) : vs[r+1];
  float f0 = __fdiv_rn(__fadd_rn(c0, c1), 1.999f);
  float f1 = __fdiv_rn(__fadd_rn(c1, c2), 2.001f);

  bool ns = (mnf == mxf);
  float4 q;
  q.x = ns ? 0.0f : mnf;                       // vmin_use
  q.y = ns ? 1.0f : __fsub_rn(mxf, mnf);       // range_use
  q.z = ns ? 1.0f : __fsub_rn(f1, f0);         // (f1-f0)_use
  q.w = ns ? 0.0f : f0;                        // f0_use
  params[b*NG + g] = q;
}

// ---- Pass 6: per-element apply, fp32 replicating reference op order ----
static __device__ __forceinline__ float apply_one(float p, int g, const float4* __restrict__ sp){
  float4 q = sp[g];
  float t1  = __fsub_rn(p, q.x);
  float t3  = __fdiv_rn(t1, q.y);
  float t5  = __fmul_rn(t3, q.z);
  float tmp = __fadd_rn(t5, q.w);
  bool bad = __builtin_isnan(tmp) || (tmp == 0.0f);
  float s = __fdiv_rn(p, bad ? 1.0f : tmp);
  bool bad2 = bad || __builtin_isnan(s) || __builtin_isinf(s);
  float sc = bad2 ? 0.0f : s;
  return __fmul_rn(p, sc);
}

__global__ __launch_bounds__(256) void k_apply(const float* __restrict__ pr,
                                               const int* __restrict__ vr,
                                               const float4* __restrict__ params,
                                               float* __restrict__ out){
  __shared__ float4 sp[NG];
  const int t = threadIdx.x;
  const int b = blockIdx.x / CD;
  const int c = blockIdx.x % CD;

  sp[t] = params[b*NG + t];
  __syncthreads();

  const size_t base = (size_t)b*NN + (size_t)c*ELD;
  const float4* p4 = (const float4*)(pr + base);
  const int4*  v4 = (const int4*)(vr + base);
  float4* o4 = (float4*)(out + base);

#pragma unroll
  for (int i = 0; i < ELD/1024; i++){
    float4 p = p4[i*256 + t];
    int4   v = v4[i*256 + t];
    float4 r;
    r.x = apply_one(p.x, v.x, sp);
    r.y = apply_one(p.y, v.y, sp);
    r.z = apply_one(p.z, v.z, sp);
    r.w = apply_one(p.w, v.w, sp);
    o4[i*256 + t] = r;
  }
}

extern "C" void kernel_launch(void* const* d_in, const int* in_sizes, int n_in,
                              void* d_out, int out_size, void* d_ws, size_t ws_size,
                              hipStream_t stream){
  const float* pr        = (const float*)d_in[0];
  const float* inp_means = (const float*)d_in[1];
  const int*   vr        = (const int*)d_in[2];
  const float* W         = (const float*)d_in[3];
  float* out = (float*)d_out;

  char* ws = (char*)d_ws;
  size_t o = 0;
  unsigned* cnt     = (unsigned*)(ws + o); o += (size_t)NB*NC*NG*4;  // 4 MB
  unsigned* grpbase = (unsigned*)(ws + o); o += (size_t)NB*NG*4;     // 32 KB
  unsigned* grplen  = (unsigned*)(ws + o); o += (size_t)NB*NG*4;
  float*    gsum    = (float*)   (ws + o); o += (size_t)NB*NG*4;
  float*    gmn     = (float*)   (ws + o); o += (size_t)NB*NG*4;
  float*    gmx     = (float*)   (ws + o); o += (size_t)NB*NG*4;
  float4*   params  = (float4*)  (ws + o); o += (size_t)NB*NG*16;    // 128 KB
  // sorted values live in d_out (fully overwritten by k_apply afterwards)
  float* sorted = out;

  k_count   <<<NB*NC, 256, 0, stream>>>(vr, cnt);
  k_offsets <<<NB,     NG, 0, stream>>>(cnt, grpbase, grplen);
  k_scatter <<<NB*NC,  64, 0, stream>>>(pr, vr, cnt, sorted);
  k_sum     <<<NB*NG,  64, 0, stream>>>(sorted, grpbase, grplen, gsum, gmn, gmx);
  k_pipeline<<<NB,     NG, 0, stream>>>(gsum, gmn, gmx, inp_means, W, params);
  k_apply   <<<NB*CD, 256, 0, stream>>>(pr, vr, params, out);
}

// Round 4
// 204.856 us; speedup vs baseline: 2.6451x; 1.6293x over previous
//
#include <hip/hip_runtime.h>
#include <math.h>

#define NB 32
#define NN 262144
#define NG 256
#define NC 32             // chunks per batch (sort passes)
#define CH (NN/NC)        // 8192 elements per chunk
#define SC (CH/4)         // 2048 elements per wave (4 waves/block)
#define CD 64             // chunks per batch, apply pass
#define ELD (NN/CD)       // 4096 elements per apply block
#define LCAP 2048         // LDS floats per group in k_sum (mean len 1024, sigma~32)

// ---------------- Pass 1: per-(batch,chunk,group) counts ----------------
__global__ __launch_bounds__(256) void k_count(const int* __restrict__ vr,
                                               unsigned* __restrict__ cnt){
  __shared__ unsigned scnt[NG];
  const int t = threadIdx.x;
  scnt[t] = 0u;
  __syncthreads();

  const int b = blockIdx.x / NC;
  const int c = blockIdx.x % NC;
  const size_t base = (size_t)b*NN + (size_t)c*CH;
  const int4* v4 = (const int4*)(vr + base);

#pragma unroll
  for (int i = 0; i < CH/1024; i++){
    int4 v = v4[i*256 + t];
    atomicAdd(&scnt[v.x], 1u);
    atomicAdd(&scnt[v.y], 1u);
    atomicAdd(&scnt[v.z], 1u);
    atomicAdd(&scnt[v.w], 1u);
  }
  __syncthreads();
  cnt[(size_t)(b*NC + c)*NG + t] = scnt[t];
}

// ---- Pass 2: rewrite cnt into absolute scatter offsets; emit group base/len ----
__global__ __launch_bounds__(256) void k_offsets(unsigned* __restrict__ cnt,
                                                 unsigned* __restrict__ grpbase,
                                                 unsigned* __restrict__ grplen){
  const int b = blockIdx.x;
  const int g = threadIdx.x;
  unsigned tot = 0;
  for (int c = 0; c < NC; c++) tot += cnt[(size_t)(b*NC + c)*NG + g];

  __shared__ unsigned ss[NG];
  ss[g] = tot; __syncthreads();
  for (int d = 1; d < NG; d <<= 1){
    unsigned v = (g >= d) ? ss[g - d] : 0u;
    __syncthreads();
    ss[g] += v;
    __syncthreads();
  }
  unsigned base = ss[g] - tot;   // exclusive prefix over groups

  unsigned run = base;
  for (int c = 0; c < NC; c++){
    size_t idx = (size_t)(b*NC + c)*NG + g;
    unsigned x = cnt[idx];
    cnt[idx] = run;
    run += x;
  }
  grpbase[b*NG + g] = base;
  grplen [b*NG + g] = tot;
}

// ---- Pass 3: LDS-staged stable sort of each chunk + coalesced full-line flush ----
// Stability: waves own contiguous sub-chunks in wave-index order; per-wave running
// counters are seeded with cross-wave prefix so the global element order is kept
// bit-exactly (the fp32 sum chain downstream depends on it).
__global__ __launch_bounds__(256) void k_scatter(const float* __restrict__ pr,
                                                 const int* __restrict__ vr,
                                                 const unsigned* __restrict__ off,
                                                 float* __restrict__ sorted){
  __shared__ float vbuf[CH];            // 32 KB sorted values
  __shared__ unsigned char gbuf[CH];    // 8 KB group id per sorted slot
  __shared__ unsigned wcnt[4][NG];      // per-wave histogram -> running counters
  __shared__ unsigned bias[NG];         // global_dest - local_base per group
  __shared__ unsigned ss[NG];           // scan scratch
  const int t    = threadIdx.x;
  const int lane = t & 63;
  const int w    = t >> 6;
  const int b = blockIdx.x / NC;
  const int c = blockIdx.x % NC;
  const size_t base = (size_t)b*NN + (size_t)c*CH;

#pragma unroll
  for (int k = 0; k < 4; k++) wcnt[k][t] = 0u;
  __syncthreads();

  // phase 1: per-wave histogram over its sub-chunk
  {
    const int4* v4 = (const int4*)(vr + base + (size_t)w*SC);
#pragma unroll
    for (int i = 0; i < SC/256; i++){
      int4 v = v4[i*64 + lane];
      atomicAdd(&wcnt[w][v.x], 1u);
      atomicAdd(&wcnt[w][v.y], 1u);
      atomicAdd(&wcnt[w][v.z], 1u);
      atomicAdd(&wcnt[w][v.w], 1u);
    }
  }
  __syncthreads();

  // phase 2: local offsets (thread t == group id)
  {
    unsigned c0 = wcnt[0][t], c1 = wcnt[1][t], c2 = wcnt[2][t], c3 = wcnt[3][t];
    unsigned tot = c0 + c1 + c2 + c3;
    ss[t] = tot; __syncthreads();
    for (int d = 1; d < NG; d <<= 1){
      unsigned v = (t >= d) ? ss[t - d] : 0u;
      __syncthreads();
      ss[t] += v;
      __syncthreads();
    }
    unsigned lb = ss[t] - tot;              // local exclusive prefix over groups
    wcnt[0][t] = lb;
    wcnt[1][t] = lb + c0;
    wcnt[2][t] = lb + c0 + c1;
    wcnt[3][t] = lb + c0 + c1 + c2;
    bias[t] = off[(size_t)(b*NC + c)*NG + t] - lb;
  }
  __syncthreads();

  // phase 3: stable scatter into LDS (per wave, element order)
  {
    const unsigned long long below = (lane == 0) ? 0ull : ((1ull << lane) - 1ull);
    const size_t sb = base + (size_t)w*SC;
    for (int s = 0; s < SC/64; s++){
      float p = pr[sb + s*64 + lane];
      int   g = vr[sb + s*64 + lane];
      unsigned long long mask = ~0ull;
#pragma unroll
      for (int bit = 0; bit < 8; bit++){
        int bv = (g >> bit) & 1;
        unsigned long long bal = __ballot(bv);
        mask &= bv ? bal : ~bal;
      }
      int rank = __popcll(mask & below);
      unsigned old = wcnt[w][g];                 // all lanes read pre-update value
      if (rank == 0) wcnt[w][g] = old + (unsigned)__popcll(mask);
      vbuf[old + (unsigned)rank] = p;
      gbuf[old + (unsigned)rank] = (unsigned char)g;
    }
  }
  __syncthreads();

  // phase 4: coalesced flush (consecutive p -> consecutive dest within group runs)
  {
    float* dst = sorted + (size_t)b*NN;
    for (int p = t; p < CH; p += 256){
      unsigned g = gbuf[p];
      dst[bias[g] + (unsigned)p] = vbuf[p];
    }
  }
}

// ---- Pass 4: one wave per (batch,group): stage group in LDS, lane0 runs the
//      bit-exact element-order fp32 chain; wave-reduce exact min/max ----
__global__ __launch_bounds__(64) void k_sum(const float* __restrict__ sorted,
                                            const unsigned* __restrict__ grpbase,
                                            const unsigned* __restrict__ grplen,
                                            float* __restrict__ gsum,
                                            float* __restrict__ gmn,
                                            float* __restrict__ gmx){
  __shared__ float sm[LCAP];
  const int lane = threadIdx.x;
  const int b = blockIdx.x / NG;
  const int g = blockIdx.x % NG;

  const unsigned base = grpbase[b*NG + g];
  const unsigned len  = grplen [b*NG + g];
  const float* src = sorted + (size_t)b*NN + base;

  float mn = INFINITY, mx = -INFINITY;
  for (unsigned i = lane; i < len; i += 64){
    float v = src[i];
    mn = fminf(mn, v);
    mx = fmaxf(mx, v);
    if (i < LCAP) sm[i] = v;
  }
#pragma unroll
  for (int d = 32; d > 0; d >>= 1){
    mn = fminf(mn, __shfl_down(mn, d));
    mx = fmaxf(mx, __shfl_down(mx, d));
  }
  __syncthreads();

  if (lane == 0){
    const unsigned lim = (len < LCAP) ? len : LCAP;
    float s = 0.0f;
    unsigned i = 0;
    for (; i + 8 <= lim; i += 8){
      float v0 = sm[i+0], v1 = sm[i+1], v2 = sm[i+2], v3 = sm[i+3];
      float v4 = sm[i+4], v5 = sm[i+5], v6 = sm[i+6], v7 = sm[i+7];
      s = __fadd_rn(s, v0); s = __fadd_rn(s, v1);
      s = __fadd_rn(s, v2); s = __fadd_rn(s, v3);
      s = __fadd_rn(s, v4); s = __fadd_rn(s, v5);
      s = __fadd_rn(s, v6); s = __fadd_rn(s, v7);
    }
    for (; i < lim; i++) s = __fadd_rn(s, sm[i]);
    for (unsigned j = lim; j < len; j++) s = __fadd_rn(s, src[j]); // safety tail
    gsum[b*NG + g] = s;
    gmn [b*NG + g] = mn;
    gmx [b*NG + g] = mx;
  }
}

// ---- Pass 5: per-batch group pipeline (blend, stable rank, f0/f1, no_scale) ----
__global__ __launch_bounds__(256) void k_pipeline(const float* __restrict__ gsum,
                                                  const float* __restrict__ gmn,
                                                  const float* __restrict__ gmx,
                                                  const float* __restrict__ inp_means,
                                                  const float* __restrict__ Wv,
                                                  float4* __restrict__ params){
  const int b = blockIdx.x;
  const int g = threadIdx.x;
  __shared__ float vm[NG];
  __shared__ float vs[NG];

  const float s   = gsum[b*NG + g];   // empty group: len==0 -> s==0 (matches where(vany,...))
  const float mnf = gmn [b*NG + g];
  const float mxf = gmx [b*NG + g];
  const float W0 = Wv[0], W1 = Wv[1];
  float mean = __fdiv_rn(__fadd_rn(__fmul_rn(inp_means[b*NG + g], W0),
                                   __fmul_rn(s, W1)),
                         __fadd_rn(W0, W1));
  vm[g] = mean;
  __syncthreads();

  // stable rank == position after stable argsort
  int r = 0;
  for (int j = 0; j < NG; j++){
    float x = vm[j];
    r += (x < mean) || (x == mean && j < g);
  }
  vs[r] = mean;
  __syncthreads();

  float c0 = (r == 0)    ? vs[0]                     : vs[r-1];
  float c1 = vs[r];
  float c2 = (r == NG-1) ? __fmul_rn(vs[NG-1], 2.0f) : vs[r+1];
  float f0 = __fdiv_rn(__fadd_rn(c0, c1), 1.999f);
  float f1 = __fdiv_rn(__fadd_rn(c1, c2), 2.001f);

  bool ns = (mnf == mxf);
  float4 q;
  q.x = ns ? 0.0f : mnf;                       // vmin_use
  q.y = ns ? 1.0f : __fsub_rn(mxf, mnf);       // range_use
  q.z = ns ? 1.0f : __fsub_rn(f1, f0);         // (f1-f0)_use
  q.w = ns ? 0.0f : f0;                        // f0_use
  params[b*NG + g] = q;
}

// ---- Pass 6: per-element apply, fp32 replicating reference op order ----
static __device__ __forceinline__ float apply_one(float p, int g, const float4* __restrict__ sp){
  float4 q = sp[g];
  float t1  = __fsub_rn(p, q.x);
  float t3  = __fdiv_rn(t1, q.y);
  float t5  = __fmul_rn(t3, q.z);
  float tmp = __fadd_rn(t5, q.w);
  bool bad = __builtin_isnan(tmp) || (tmp == 0.0f);
  float s = __fdiv_rn(p, bad ? 1.0f : tmp);
  bool bad2 = bad || __builtin_isnan(s) || __builtin_isinf(s);
  float sc = bad2 ? 0.0f : s;
  return __fmul_rn(p, sc);
}

__global__ __launch_bounds__(256) void k_apply(const float* __restrict__ pr,
                                               const int* __restrict__ vr,
                                               const float4* __restrict__ params,
                                               float* __restrict__ out){
  __shared__ float4 sp[NG];
  const int t = threadIdx.x;
  const int b = blockIdx.x / CD;
  const int c = blockIdx.x % CD;

  sp[t] = params[b*NG + t];
  __syncthreads();

  const size_t base = (size_t)b*NN + (size_t)c*ELD;
  const float4* p4 = (const float4*)(pr + base);
  const int4*  v4 = (const int4*)(vr + base);
  float4* o4 = (float4*)(out + base);

#pragma unroll
  for (int i = 0; i < ELD/1024; i++){
    float4 p = p4[i*256 + t];
    int4   v = v4[i*256 + t];
    float4 r;
    r.x = apply_one(p.x, v.x, sp);
    r.y = apply_one(p.y, v.y, sp);
    r.z = apply_one(p.z, v.z, sp);
    r.w = apply_one(p.w, v.w, sp);
    o4[i*256 + t] = r;
  }
}

extern "C" void kernel_launch(void* const* d_in, const int* in_sizes, int n_in,
                              void* d_out, int out_size, void* d_ws, size_t ws_size,
                              hipStream_t stream){
  const float* pr        = (const float*)d_in[0];
  const float* inp_means = (const float*)d_in[1];
  const int*   vr        = (const int*)d_in[2];
  const float* W         = (const float*)d_in[3];
  float* out = (float*)d_out;

  char* ws = (char*)d_ws;
  size_t o = 0;
  unsigned* cnt     = (unsigned*)(ws + o); o += (size_t)NB*NC*NG*4;  // 1 MB
  unsigned* grpbase = (unsigned*)(ws + o); o += (size_t)NB*NG*4;     // 32 KB
  unsigned* grplen  = (unsigned*)(ws + o); o += (size_t)NB*NG*4;
  float*    gsum    = (float*)   (ws + o); o += (size_t)NB*NG*4;
  float*    gmn     = (float*)   (ws + o); o += (size_t)NB*NG*4;
  float*    gmx     = (float*)   (ws + o); o += (size_t)NB*NG*4;
  float4*   params  = (float4*)  (ws + o); o += (size_t)NB*NG*16;    // 128 KB
  // sorted values live in d_out (fully overwritten by k_apply afterwards)
  float* sorted = out;

  k_count   <<<NB*NC, 256, 0, stream>>>(vr, cnt);
  k_offsets <<<NB,     NG, 0, stream>>>(cnt, grpbase, grplen);
  k_scatter <<<NB*NC, 256, 0, stream>>>(pr, vr, cnt, sorted);
  k_sum     <<<NB*NG,  64, 0, stream>>>(sorted, grpbase, grplen, gsum, gmn, gmx);
  k_pipeline<<<NB,     NG, 0, stream>>>(gsum, gmn, gmx, inp_means, W, params);
  k_apply   <<<NB*CD, 256, 0, stream>>>(pr, vr, params, out);
}

// Round 5
// 196.999 us; speedup vs baseline: 2.7506x; 1.0399x over previous
//
#include <hip/hip_runtime.h>
#include <math.h>

#define NB 32
#define NN 262144
#define NG 256
#define NC 64             // chunks per batch (sort passes)
#define CH (NN/NC)        // 4096 elements per chunk
#define SC (CH/4)         // 1024 elements per wave (4 waves/block)
#define CD 64             // chunks per batch, apply pass
#define ELD (NN/CD)       // 4096 elements per apply block
#define LCAP 1536         // LDS floats per group in k_sum (mean 1024, +16 sigma)

// ---------------- Pass 1: per-(batch,chunk,group) counts ----------------
__global__ __launch_bounds__(256) void k_count(const int* __restrict__ vr,
                                               unsigned* __restrict__ cnt){
  __shared__ unsigned scnt[NG];
  const int t = threadIdx.x;
  scnt[t] = 0u;
  __syncthreads();

  const int b = blockIdx.x / NC;
  const int c = blockIdx.x % NC;
  const size_t base = (size_t)b*NN + (size_t)c*CH;
  const int4* v4 = (const int4*)(vr + base);

#pragma unroll
  for (int i = 0; i < CH/1024; i++){
    int4 v = v4[i*256 + t];
    atomicAdd(&scnt[v.x], 1u);
    atomicAdd(&scnt[v.y], 1u);
    atomicAdd(&scnt[v.z], 1u);
    atomicAdd(&scnt[v.w], 1u);
  }
  __syncthreads();
  cnt[(size_t)(b*NC + c)*NG + t] = scnt[t];
}

// ---- Pass 2: rewrite cnt into absolute scatter offsets; emit group base/len ----
__global__ __launch_bounds__(256) void k_offsets(unsigned* __restrict__ cnt,
                                                 unsigned* __restrict__ grpbase,
                                                 unsigned* __restrict__ grplen){
  const int b = blockIdx.x;
  const int g = threadIdx.x;
  unsigned tot = 0;
#pragma unroll 8
  for (int c = 0; c < NC; c++) tot += cnt[(size_t)(b*NC + c)*NG + g];

  __shared__ unsigned ss[NG];
  ss[g] = tot; __syncthreads();
  for (int d = 1; d < NG; d <<= 1){
    unsigned v = (g >= d) ? ss[g - d] : 0u;
    __syncthreads();
    ss[g] += v;
    __syncthreads();
  }
  unsigned base = ss[g] - tot;   // exclusive prefix over groups

  unsigned run = base;
  for (int c = 0; c < NC; c++){
    size_t idx = (size_t)(b*NC + c)*NG + g;
    unsigned x = cnt[idx];
    cnt[idx] = run;
    run += x;
  }
  grpbase[b*NG + g] = base;
  grplen [b*NG + g] = tot;
}

// ---- Pass 3: LDS-staged stable sort of each chunk + coalesced flush ----
// Stability: waves own contiguous sub-chunks in wave-index order; per-wave
// running counters seeded with cross-wave prefix -> global element order kept
// bit-exactly (the fp32 sum chain downstream depends on it).
__global__ __launch_bounds__(256) void k_scatter(const float* __restrict__ pr,
                                                 const int* __restrict__ vr,
                                                 const unsigned* __restrict__ off,
                                                 float* __restrict__ sorted){
  __shared__ float vbuf[CH];            // 16 KB sorted values
  __shared__ unsigned graw32[CH/4];     // 4 KB raw group ids (packed u8x4, elem order)
  __shared__ unsigned char gbuf[CH];    // 4 KB group id per sorted slot
  __shared__ unsigned wcnt[4][NG];      // per-wave histogram -> running counters
  __shared__ unsigned bias[NG];         // global_dest - local_base per group
  __shared__ unsigned ss[NG];           // scan scratch
  const int t    = threadIdx.x;
  const int lane = t & 63;
  const int w    = t >> 6;
  const int b = blockIdx.x / NC;
  const int c = blockIdx.x % NC;
  const size_t base = (size_t)b*NN + (size_t)c*CH;

#pragma unroll
  for (int k = 0; k < 4; k++) wcnt[k][t] = 0u;
  __syncthreads();

  // phase 1: per-wave histogram over its sub-chunk + stage packed group ids
  {
    const int4* v4 = (const int4*)(vr + base + (size_t)w*SC);
#pragma unroll
    for (int i = 0; i < SC/256; i++){      // 4 iters
      int4 v = v4[i*64 + lane];
      atomicAdd(&wcnt[w][v.x], 1u);
      atomicAdd(&wcnt[w][v.y], 1u);
      atomicAdd(&wcnt[w][v.z], 1u);
      atomicAdd(&wcnt[w][v.w], 1u);
      graw32[w*(SC/4) + i*64 + lane] =
        (unsigned)v.x | ((unsigned)v.y << 8) | ((unsigned)v.z << 16) | ((unsigned)v.w << 24);
    }
  }
  __syncthreads();

  // phase 2: local offsets (thread t == group id)
  {
    unsigned c0 = wcnt[0][t], c1 = wcnt[1][t], c2 = wcnt[2][t], c3 = wcnt[3][t];
    unsigned tot = c0 + c1 + c2 + c3;
    ss[t] = tot; __syncthreads();
    for (int d = 1; d < NG; d <<= 1){
      unsigned v = (t >= d) ? ss[t - d] : 0u;
      __syncthreads();
      ss[t] += v;
      __syncthreads();
    }
    unsigned lb = ss[t] - tot;              // local exclusive prefix over groups
    wcnt[0][t] = lb;
    wcnt[1][t] = lb + c0;
    wcnt[2][t] = lb + c0 + c1;
    wcnt[3][t] = lb + c0 + c1 + c2;
    bias[t] = off[(size_t)(b*NC + c)*NG + t] - lb;
  }
  __syncthreads();

  // phase 3: stable scatter into LDS (per wave, element order; g fed from LDS)
  {
    const unsigned long long below = (lane == 0) ? 0ull : ((1ull << lane) - 1ull);
    const float* psrc = pr + base + (size_t)w*SC;
    const int shft = (lane & 3) * 8;
    for (int s = 0; s < SC/64; s++){       // 16 stripes
      float p = psrc[s*64 + lane];
      // same-word broadcast read: 4 lanes share one dword, free on LDS
      unsigned packed = graw32[w*(SC/4) + s*16 + (lane >> 2)];
      int g = (int)((packed >> shft) & 255u);
      unsigned long long mask = ~0ull;
#pragma unroll
      for (int bit = 0; bit < 8; bit++){
        int bv = (g >> bit) & 1;
        unsigned long long bal = __ballot(bv);
        mask &= bv ? bal : ~bal;
      }
      int rank = __popcll(mask & below);
      unsigned old = wcnt[w][g];                 // all lanes read pre-update value
      if (rank == 0) wcnt[w][g] = old + (unsigned)__popcll(mask);
      vbuf[old + (unsigned)rank] = p;
      gbuf[old + (unsigned)rank] = (unsigned char)g;
    }
  }
  __syncthreads();

  // phase 4: coalesced flush (consecutive p -> consecutive dest within group runs)
  {
    float* dst = sorted + (size_t)b*NN;
    const unsigned* gbuf32 = (const unsigned*)gbuf;
#pragma unroll
    for (int k = 0; k < CH/256; k++){
      int p = k*256 + t;
      unsigned packed = gbuf32[p >> 2];    // broadcast within 4 threads
      unsigned g = (packed >> ((p & 3) * 8)) & 255u;
      dst[bias[g] + (unsigned)p] = vbuf[p];
    }
  }
}

// ---- Pass 4: one wave per (batch,group): stage group in LDS, lane0 runs the
//      bit-exact element-order fp32 chain; wave-reduce exact min/max ----
__global__ __launch_bounds__(64) void k_sum(const float* __restrict__ sorted,
                                            const unsigned* __restrict__ grpbase,
                                            const unsigned* __restrict__ grplen,
                                            float* __restrict__ gsum,
                                            float* __restrict__ gmn,
                                            float* __restrict__ gmx){
  __shared__ float4 sm4[LCAP/4];
  float* sm = (float*)sm4;
  const int lane = threadIdx.x;
  const int b = blockIdx.x / NG;
  const int g = blockIdx.x % NG;

  const unsigned base = grpbase[b*NG + g];
  const unsigned len  = grplen [b*NG + g];
  const float* src = sorted + (size_t)b*NN + base;

  float mn = INFINITY, mx = -INFINITY;
  for (unsigned i = lane; i < len; i += 64){
    float v = src[i];
    mn = fminf(mn, v);
    mx = fmaxf(mx, v);
    if (i < LCAP) sm[i] = v;
  }
#pragma unroll
  for (int d = 32; d > 0; d >>= 1){
    mn = fminf(mn, __shfl_down(mn, d));
    mx = fmaxf(mx, __shfl_down(mx, d));
  }
  __syncthreads();

  if (lane == 0){
    const unsigned lim = (len < LCAP) ? len : LCAP;
    float s = 0.0f;
    unsigned i = 0;
    for (; i + 8 <= lim; i += 8){
      // two ds_read_b128 batched ahead of the dependent add chain
      float4 a = sm4[i/4], c = sm4[i/4 + 1];
      s = __fadd_rn(s, a.x); s = __fadd_rn(s, a.y);
      s = __fadd_rn(s, a.z); s = __fadd_rn(s, a.w);
      s = __fadd_rn(s, c.x); s = __fadd_rn(s, c.y);
      s = __fadd_rn(s, c.z); s = __fadd_rn(s, c.w);
    }
    for (; i < lim; i++) s = __fadd_rn(s, sm[i]);
    for (unsigned j = lim; j < len; j++) s = __fadd_rn(s, src[j]); // safety tail
    gsum[b*NG + g] = s;
    gmn [b*NG + g] = mn;
    gmx [b*NG + g] = mx;
  }
}

// ---- Pass 5: per-batch group pipeline (blend, stable rank, f0/f1, no_scale) ----
__global__ __launch_bounds__(256) void k_pipeline(const float* __restrict__ gsum,
                                                  const float* __restrict__ gmn,
                                                  const float* __restrict__ gmx,
                                                  const float* __restrict__ inp_means,
                                                  const float* __restrict__ Wv,
                                                  float4* __restrict__ params){
  const int b = blockIdx.x;
  const int g = threadIdx.x;
  __shared__ float vm[NG];
  __shared__ float vs[NG];

  const float s   = gsum[b*NG + g];   // empty group: len==0 -> s==0 (matches where(vany,...))
  const float mnf = gmn [b*NG + g];
  const float mxf = gmx [b*NG + g];
  const float W0 = Wv[0], W1 = Wv[1];
  float mean = __fdiv_rn(__fadd_rn(__fmul_rn(inp_means[b*NG + g], W0),
                                   __fmul_rn(s, W1)),
                         __fadd_rn(W0, W1));
  vm[g] = mean;
  __syncthreads();

  // stable rank == position after stable argsort
  int r = 0;
  for (int j = 0; j < NG; j++){
    float x = vm[j];
    r += (x < mean) || (x == mean && j < g);
  }
  vs[r] = mean;
  __syncthreads();

  float c0 = (r == 0)    ? vs[0]                     : vs[r-1];
  float c1 = vs[r];
  float c2 = (r == NG-1) ? __fmul_rn(vs[NG-1], 2.0f) : vs[r+1];
  float f0 = __fdiv_rn(__fadd_rn(c0, c1), 1.999f);
  float f1 = __fdiv_rn(__fadd_rn(c1, c2), 2.001f);

  bool ns = (mnf == mxf);
  float4 q;
  q.x = ns ? 0.0f : mnf;                       // vmin_use
  q.y = ns ? 1.0f : __fsub_rn(mxf, mnf);       // range_use
  q.z = ns ? 1.0f : __fsub_rn(f1, f0);         // (f1-f0)_use
  q.w = ns ? 0.0f : f0;                        // f0_use
  params[b*NG + g] = q;
}

// ---- Pass 6: per-element apply, fp32 replicating reference op order ----
static __device__ __forceinline__ float apply_one(float p, int g, const float4* __restrict__ sp){
  float4 q = sp[g];
  float t1  = __fsub_rn(p, q.x);
  float t3  = __fdiv_rn(t1, q.y);
  float t5  = __fmul_rn(t3, q.z);
  float tmp = __fadd_rn(t5, q.w);
  bool bad = __builtin_isnan(tmp) || (tmp == 0.0f);
  float s = __fdiv_rn(p, bad ? 1.0f : tmp);
  bool bad2 = bad || __builtin_isnan(s) || __builtin_isinf(s);
  float sc = bad2 ? 0.0f : s;
  return __fmul_rn(p, sc);
}

__global__ __launch_bounds__(256) void k_apply(const float* __restrict__ pr,
                                               const int* __restrict__ vr,
                                               const float4* __restrict__ params,
                                               float* __restrict__ out){
  __shared__ float4 sp[NG];
  const int t = threadIdx.x;
  const int b = blockIdx.x / CD;
  const int c = blockIdx.x % CD;

  sp[t] = params[b*NG + t];
  __syncthreads();

  const size_t base = (size_t)b*NN + (size_t)c*ELD;
  const float4* p4 = (const float4*)(pr + base);
  const int4*  v4 = (const int4*)(vr + base);
  float4* o4 = (float4*)(out + base);

#pragma unroll
  for (int i = 0; i < ELD/1024; i++){
    float4 p = p4[i*256 + t];
    int4   v = v4[i*256 + t];
    float4 r;
    r.x = apply_one(p.x, v.x, sp);
    r.y = apply_one(p.y, v.y, sp);
    r.z = apply_one(p.z, v.z, sp);
    r.w = apply_one(p.w, v.w, sp);
    o4[i*256 + t] = r;
  }
}

extern "C" void kernel_launch(void* const* d_in, const int* in_sizes, int n_in,
                              void* d_out, int out_size, void* d_ws, size_t ws_size,
                              hipStream_t stream){
  const float* pr        = (const float*)d_in[0];
  const float* inp_means = (const float*)d_in[1];
  const int*   vr        = (const int*)d_in[2];
  const float* W         = (const float*)d_in[3];
  float* out = (float*)d_out;

  char* ws = (char*)d_ws;
  size_t o = 0;
  unsigned* cnt     = (unsigned*)(ws + o); o += (size_t)NB*NC*NG*4;  // 2 MB
  unsigned* grpbase = (unsigned*)(ws + o); o += (size_t)NB*NG*4;     // 32 KB
  unsigned* grplen  = (unsigned*)(ws + o); o += (size_t)NB*NG*4;
  float*    gsum    = (float*)   (ws + o); o += (size_t)NB*NG*4;
  float*    gmn     = (float*)   (ws + o); o += (size_t)NB*NG*4;
  float*    gmx     = (float*)   (ws + o); o += (size_t)NB*NG*4;
  float4*   params  = (float4*)  (ws + o); o += (size_t)NB*NG*16;    // 128 KB
  // sorted values live in d_out (fully overwritten by k_apply afterwards)
  float* sorted = out;

  k_count   <<<NB*NC, 256, 0, stream>>>(vr, cnt);
  k_offsets <<<NB,     NG, 0, stream>>>(cnt, grpbase, grplen);
  k_scatter <<<NB*NC, 256, 0, stream>>>(pr, vr, cnt, sorted);
  k_sum     <<<NB*NG,  64, 0, stream>>>(sorted, grpbase, grplen, gsum, gmn, gmx);
  k_pipeline<<<NB,     NG, 0, stream>>>(gsum, gmn, gmx, inp_means, W, params);
  k_apply   <<<NB*CD, 256, 0, stream>>>(pr, vr, params, out);
}